// Round 1
// baseline (178.774 us; speedup 1.0000x reference)
//
#include <hip/hip_runtime.h>
#include <hip/hip_bf16.h>
#include <math.h>

typedef __bf16 bf16x8 __attribute__((ext_vector_type(8)));
typedef float  f32x4  __attribute__((ext_vector_type(4)));

#define M_DIM 16384
#define N_DIM 512
#define K_DIM 512
#define TBL_N 1024

__device__ inline bf16x8 cvt8(float4 a, float4 b) {
    bf16x8 r;
    r[0] = (__bf16)a.x; r[1] = (__bf16)a.y; r[2] = (__bf16)a.z; r[3] = (__bf16)a.w;
    r[4] = (__bf16)b.x; r[5] = (__bf16)b.y; r[6] = (__bf16)b.z; r[7] = (__bf16)b.w;
    return r;
}

// ---------------- fused: fp32 load -> bf16 reg-stage -> GEMM -> HH ----------------
// R10: single kernel. Removes the bf16 intermediate round-trip (convert kernel
// wrote 16.8 MiB bf16 that gemm immediately re-read) and the serial launch gap.
// Tile 128m x 64n, grid 1024 = 4 blocks/CU, 2 barriers/K-tile (R8 structure).
// Staging is register-prefetched (fallback-style): global fp32 loads for tile
// t+1 are issued before tile t's LDS write, hiding HBM latency under MFMA.
// XOR swizzle now applied on the REGISTER WRITE side (LDS[r][c] = global chunk
// c^(r&7)); read side identical to the DMA version (both-sides involution).
__global__ __launch_bounds__(256, 4)
void snn_fused_kernel(const float* __restrict__ x, const float* __restrict__ W,
                      const float* __restrict__ gNa_p, const float* __restrict__ gK_p,
                      const float* __restrict__ gL_p, float* __restrict__ out)
{
    __shared__ __bf16 sW[64 * 64];     // W-tile: 64 gn rows x 64 k
    __shared__ __bf16 sX[128 * 64];    // x-tile: 128 gm rows x 64 k
    __shared__ float  tbl[TBL_N + 1];

    const int tid = threadIdx.x;

    // XCD swizzle: each XCD owns 16 bm tiles; consecutive slots sweep all 8 bn
    // for one bm so the x-rows are L2-resident for the reuse.
    const int id   = blockIdx.x;            // 0..1023
    const int xcd  = id & 7;
    const int slot = id >> 3;               // 0..127
    const int bm   = xcd * 16 + (slot >> 3);    // 0..127
    const int bn   = slot & 7;                  // 0..7

    const int wv   = tid >> 6;
    const int ln   = tid & 63;
    const int lr   = ln & 15;
    const int quad = ln >> 4;

    // staging pattern: lane covers row rw of an 8-row group, 16B-chunk ch.
    // Source column is XOR-swizzled (chx), LDS dest is linear chunk ch =>
    // LDS[r][c] holds global chunk c^(r&7); MFMA read applies the same XOR.
    const int rw  = ln >> 3;                // 0..7
    const int ch  = ln & 7;                 // 0..7
    const int chx = (ch ^ rw) * 8;          // swizzled k-offset within tile

    const float* wSrc = W + ((long)bn * 64 + 16 * wv + rw) * K_DIM + chx;
    const float* xSrc = x + ((long)bm * 128 + 32 * wv + rw) * K_DIM + chx;
    __bf16* wDst = sW + (16 * wv + rw) * 64 + ch * 8;
    __bf16* xDst = sX + (32 * wv + rw) * 64 + ch * 8;

    // ---- prime tile-0 prefetch regs (in flight during the table build) ----
    float4 pw[2][2], px[4][2];              // 48 VGPRs of prefetch state
    #pragma unroll
    for (int j = 0; j < 2; ++j) {
        pw[j][0] = *(const float4*)(wSrc + (long)(8 * j) * K_DIM);
        pw[j][1] = *(const float4*)(wSrc + (long)(8 * j) * K_DIM + 4);
    }
    #pragma unroll
    for (int j = 0; j < 4; ++j) {
        px[j][0] = *(const float4*)(xSrc + (long)(8 * j) * K_DIM);
        px[j][1] = *(const float4*)(xSrc + (long)(8 * j) * K_DIM + 4);
    }

    // ---- exact-HH I_in(V) table ----
    {
        const float gNa = *gNa_p, gK = *gK_p, gL = *gL_p;
        for (int i = tid; i <= TBL_N; i += 256) {
            const float V = -4.0f + (8.0f / TBL_N) * i;
            const float am = 0.1f * (V + 40.0f) / (1.0f - expf(-(V + 40.0f) * 0.1f));
            const float bm_ = 4.0f * expf(-(V + 65.0f) * (1.0f / 18.0f));
            const float ah = 0.07f * expf(-(V + 65.0f) * 0.05f);
            const float bh = 1.0f / (1.0f + expf(-(V + 35.0f) * 0.1f));
            const float an = 0.01f * (V + 55.0f) / (1.0f - expf(-(V + 55.0f) * 0.1f));
            const float bn_ = 0.125f * expf(-(V + 65.0f) * 0.0125f);
            const float m = 0.05f + 0.1f * (am * 0.95f - bm_ * 0.05f);
            const float h = 0.60f + 0.1f * (ah * 0.40f - bh * 0.60f);
            const float n = 0.32f + 0.1f * (an * 0.68f - bn_ * 0.32f);
            tbl[i] = gNa * m * m * m * h * (V - 50.0f)
                   + gK * (n * n) * (n * n) * (V + 77.0f)
                   + gL * (V + 54.4f) + V;
        }
    }

    f32x4 acc[4][2] = {};   // [gn frag f][gm frag g]

    for (int t = 0; t < 8; ++t) {
        const int nk = (t + 1) * 64;
        // stage tile t into LDS; issue tile t+1 global loads before each
        // ds_write so HBM latency hides under this tile's MFMA.
        #pragma unroll
        for (int j = 0; j < 2; ++j) {
            float4 a = pw[j][0], b = pw[j][1];
            if (t < 7) {
                pw[j][0] = *(const float4*)(wSrc + (long)(8 * j) * K_DIM + nk);
                pw[j][1] = *(const float4*)(wSrc + (long)(8 * j) * K_DIM + nk + 4);
            }
            *(bf16x8*)(wDst + 8 * j * 64) = cvt8(a, b);
        }
        #pragma unroll
        for (int j = 0; j < 4; ++j) {
            float4 a = px[j][0], b = px[j][1];
            if (t < 7) {
                px[j][0] = *(const float4*)(xSrc + (long)(8 * j) * K_DIM + nk);
                px[j][1] = *(const float4*)(xSrc + (long)(8 * j) * K_DIM + nk + 4);
            }
            *(bf16x8*)(xDst + 8 * j * 64) = cvt8(a, b);
        }
        __syncthreads();   // tile t resident (also covers tbl on t=0)
        #pragma unroll
        for (int kk = 0; kk < 2; ++kk) {
            const int cidx = quad + 4 * kk;
            const int sl   = (cidx ^ (lr & 7)) * 8;
            bf16x8 aw[4], bx[2];
            #pragma unroll
            for (int f = 0; f < 4; ++f)
                aw[f] = *(const bf16x8*)(sW + (f * 16 + lr) * 64 + sl);
            #pragma unroll
            for (int g = 0; g < 2; ++g)
                bx[g] = *(const bf16x8*)(sX + (32 * wv + g * 16 + lr) * 64 + sl);
            #pragma unroll
            for (int f = 0; f < 4; ++f)
                #pragma unroll
                for (int g = 0; g < 2; ++g)
                    acc[f][g] = __builtin_amdgcn_mfma_f32_16x16x32_bf16(
                        aw[f], bx[g], acc[f][g], 0, 0, 0);
        }
        __syncthreads();   // all reads of tile t done before next overwrite
    }

    // ---- float4 epilogue: 4 consecutive gn per thread per frag ----
    float* outS = out;
    float* outV = out + (long)M_DIM * N_DIM;
    float* outW = out + 2L * M_DIM * N_DIM;

    #pragma unroll
    for (int f = 0; f < 4; ++f) {
        const int gn4 = bn * 64 + f * 16 + quad * 4;
        #pragma unroll
        for (int g = 0; g < 2; ++g) {
            const long gm  = (long)bm * 128 + 32 * wv + g * 16 + lr;
            const long idx = gm * N_DIM + gn4;
            f32x4 vS, vV, vW;
            #pragma unroll
            for (int i = 0; i < 4; ++i) {
                const float V = acc[f][g][i];
                float u = (V + 4.0f) * (TBL_N / 8.0f);
                u = fminf(fmaxf(u, 0.0f), (float)TBL_N - 0.001f);
                const int   iu = (int)u;
                const float fr = u - (float)iu;
                const float I_in = tbl[iu] + fr * (tbl[iu + 1] - tbl[iu]);
                const float v_new = -65.0f + I_in * 0.005f;
                const float spike = (v_new >= -50.0f) ? 1.0f : 0.0f;
                vS[i] = spike;
                vW[i] = (0.5f * (v_new + 65.0f) + 0.1f * spike) * 0.001f;
                vV[i] = (spike > 0.5f) ? -65.0f : v_new;
            }
            *(f32x4*)(outS + idx) = vS;
            *(f32x4*)(outV + idx) = vV;
            *(f32x4*)(outW + idx) = vW;
        }
    }
}

extern "C" void kernel_launch(void* const* d_in, const int* in_sizes, int n_in,
                              void* d_out, int out_size, void* d_ws, size_t ws_size,
                              hipStream_t stream) {
    const float* x   = (const float*)d_in[0];
    const float* W   = (const float*)d_in[1];
    const float* gNa = (const float*)d_in[2];
    const float* gK  = (const float*)d_in[3];
    const float* gL  = (const float*)d_in[4];
    float* out = (float*)d_out;
    (void)d_ws; (void)ws_size;  // workspace no longer needed: fused conversion

    hipLaunchKernelGGL(snn_fused_kernel, dim3(1024), dim3(256), 0, stream,
                       x, W, gNa, gK, gL, out);
}

// Round 2
// 162.671 us; speedup vs baseline: 1.0990x; 1.0990x over previous
//
#include <hip/hip_runtime.h>
#include <hip/hip_bf16.h>
#include <math.h>

typedef __bf16 bf16x8 __attribute__((ext_vector_type(8)));
typedef float  f32x4  __attribute__((ext_vector_type(4)));

#define M_DIM 16384
#define N_DIM 512
#define K_DIM 512
#define TBL_N 1024

__device__ inline bf16x8 cvt8(float4 a, float4 b) {
    bf16x8 r;
    r[0] = (__bf16)a.x; r[1] = (__bf16)a.y; r[2] = (__bf16)a.z; r[3] = (__bf16)a.w;
    r[4] = (__bf16)b.x; r[5] = (__bf16)b.y; r[6] = (__bf16)b.z; r[7] = (__bf16)b.w;
    return r;
}

// ---------------- fused: fp32 load -> bf16 reg-stage -> GEMM -> HH ----------------
// R11: fix the R10 spill. R10's allocator targeted 64 VGPRs under
// __launch_bounds__(256,4) and spilled ~2 float4/thread/iter to scratch
// (+69 MB WRITE_SIZE, kernel 88.6 us). Changes:
//   1. launch_bounds (256,3): VGPR cap 168, occupancy 3 blocks/CU (LDS allows 5).
//   2. W-tile prefetch dropped (-16 live VGPRs): W is 1 MB, shared by all
//      128 bm blocks -> L2-hot; JIT-load in the staging phase. x (the HBM
//      stream) keeps its register prefetch across the MFMA phase.
// Tile 128m x 64n, grid 1024, 2 barriers/K-tile. XOR swizzle applied on the
// register-WRITE side (LDS[r][c] = global chunk c^(r&7)); read side applies
// the same involution.
__global__ __launch_bounds__(256, 3)
void snn_fused_kernel(const float* __restrict__ x, const float* __restrict__ W,
                      const float* __restrict__ gNa_p, const float* __restrict__ gK_p,
                      const float* __restrict__ gL_p, float* __restrict__ out)
{
    __shared__ __bf16 sW[64 * 64];     // W-tile: 64 gn rows x 64 k
    __shared__ __bf16 sX[128 * 64];    // x-tile: 128 gm rows x 64 k
    __shared__ float  tbl[TBL_N + 1];

    const int tid = threadIdx.x;

    // XCD swizzle: each XCD owns 16 bm tiles; consecutive slots sweep all 8 bn
    // for one bm so the x-rows stay L2-resident across their reuse.
    const int id   = blockIdx.x;            // 0..1023
    const int xcd  = id & 7;
    const int slot = id >> 3;               // 0..127
    const int bm   = xcd * 16 + (slot >> 3);    // 0..127
    const int bn   = slot & 7;                  // 0..7

    const int wv   = tid >> 6;
    const int ln   = tid & 63;
    const int lr   = ln & 15;
    const int quad = ln >> 4;

    // staging pattern: lane covers row rw of an 8-row group, 16B-chunk ch.
    // Source column is XOR-swizzled (chx); LDS dest linear chunk ch =>
    // LDS[r][c] holds global chunk c^(r&7); MFMA read applies the same XOR.
    const int rw  = ln >> 3;                // 0..7
    const int ch  = ln & 7;                 // 0..7
    const int chx = (ch ^ rw) * 8;          // swizzled k-offset within tile

    const float* wSrc = W + ((long)bn * 64 + 16 * wv + rw) * K_DIM + chx;
    const float* xSrc = x + ((long)bm * 128 + 32 * wv + rw) * K_DIM + chx;
    __bf16* wDst = sW + (16 * wv + rw) * 64 + ch * 8;
    __bf16* xDst = sX + (32 * wv + rw) * 64 + ch * 8;

    // ---- prime tile-0 x-prefetch regs (in flight during the table build) ----
    float4 px[4][2];                        // 32 VGPRs of prefetch state
    #pragma unroll
    for (int j = 0; j < 4; ++j) {
        px[j][0] = *(const float4*)(xSrc + (long)(8 * j) * K_DIM);
        px[j][1] = *(const float4*)(xSrc + (long)(8 * j) * K_DIM + 4);
    }

    // ---- exact-HH I_in(V) table ----
    {
        const float gNa = *gNa_p, gK = *gK_p, gL = *gL_p;
        for (int i = tid; i <= TBL_N; i += 256) {
            const float V = -4.0f + (8.0f / TBL_N) * i;
            const float am = 0.1f * (V + 40.0f) / (1.0f - expf(-(V + 40.0f) * 0.1f));
            const float bm_ = 4.0f * expf(-(V + 65.0f) * (1.0f / 18.0f));
            const float ah = 0.07f * expf(-(V + 65.0f) * 0.05f);
            const float bh = 1.0f / (1.0f + expf(-(V + 35.0f) * 0.1f));
            const float an = 0.01f * (V + 55.0f) / (1.0f - expf(-(V + 55.0f) * 0.1f));
            const float bn_ = 0.125f * expf(-(V + 65.0f) * 0.0125f);
            const float m = 0.05f + 0.1f * (am * 0.95f - bm_ * 0.05f);
            const float h = 0.60f + 0.1f * (ah * 0.40f - bh * 0.60f);
            const float n = 0.32f + 0.1f * (an * 0.68f - bn_ * 0.32f);
            tbl[i] = gNa * m * m * m * h * (V - 50.0f)
                   + gK * (n * n) * (n * n) * (V + 77.0f)
                   + gL * (V + 54.4f) + V;
        }
    }

    f32x4 acc[4][2] = {};   // [gn frag f][gm frag g]

    for (int t = 0; t < 8; ++t) {
        const int kt = t * 64;
        const int nk = kt + 64;
        // W: JIT load (L2-hot) + stage.
        #pragma unroll
        for (int j = 0; j < 2; ++j) {
            float4 a = *(const float4*)(wSrc + (long)(8 * j) * K_DIM + kt);
            float4 b = *(const float4*)(wSrc + (long)(8 * j) * K_DIM + kt + 4);
            *(bf16x8*)(wDst + 8 * j * 64) = cvt8(a, b);
        }
        // x: consume prefetched tile t, issue tile t+1 loads before the write
        // so HBM latency hides under this tile's MFMA phase.
        #pragma unroll
        for (int j = 0; j < 4; ++j) {
            float4 a = px[j][0], b = px[j][1];
            if (t < 7) {
                px[j][0] = *(const float4*)(xSrc + (long)(8 * j) * K_DIM + nk);
                px[j][1] = *(const float4*)(xSrc + (long)(8 * j) * K_DIM + nk + 4);
            }
            *(bf16x8*)(xDst + 8 * j * 64) = cvt8(a, b);
        }
        __syncthreads();   // tile t resident (also covers tbl on t=0)
        #pragma unroll
        for (int kk = 0; kk < 2; ++kk) {
            const int cidx = quad + 4 * kk;
            const int sl   = (cidx ^ (lr & 7)) * 8;
            bf16x8 aw[4], bx[2];
            #pragma unroll
            for (int f = 0; f < 4; ++f)
                aw[f] = *(const bf16x8*)(sW + (f * 16 + lr) * 64 + sl);
            #pragma unroll
            for (int g = 0; g < 2; ++g)
                bx[g] = *(const bf16x8*)(sX + (32 * wv + g * 16 + lr) * 64 + sl);
            #pragma unroll
            for (int f = 0; f < 4; ++f)
                #pragma unroll
                for (int g = 0; g < 2; ++g)
                    acc[f][g] = __builtin_amdgcn_mfma_f32_16x16x32_bf16(
                        aw[f], bx[g], acc[f][g], 0, 0, 0);
        }
        __syncthreads();   // all reads of tile t done before next overwrite
    }

    // ---- float4 epilogue: 4 consecutive gn per thread per frag ----
    float* outS = out;
    float* outV = out + (long)M_DIM * N_DIM;
    float* outW = out + 2L * M_DIM * N_DIM;

    #pragma unroll
    for (int f = 0; f < 4; ++f) {
        const int gn4 = bn * 64 + f * 16 + quad * 4;
        #pragma unroll
        for (int g = 0; g < 2; ++g) {
            const long gm  = (long)bm * 128 + 32 * wv + g * 16 + lr;
            const long idx = gm * N_DIM + gn4;
            f32x4 vS, vV, vW;
            #pragma unroll
            for (int i = 0; i < 4; ++i) {
                const float V = acc[f][g][i];
                float u = (V + 4.0f) * (TBL_N / 8.0f);
                u = fminf(fmaxf(u, 0.0f), (float)TBL_N - 0.001f);
                const int   iu = (int)u;
                const float fr = u - (float)iu;
                const float I_in = tbl[iu] + fr * (tbl[iu + 1] - tbl[iu]);
                const float v_new = -65.0f + I_in * 0.005f;
                const float spike = (v_new >= -50.0f) ? 1.0f : 0.0f;
                vS[i] = spike;
                vW[i] = (0.5f * (v_new + 65.0f) + 0.1f * spike) * 0.001f;
                vV[i] = (spike > 0.5f) ? -65.0f : v_new;
            }
            *(f32x4*)(outS + idx) = vS;
            *(f32x4*)(outV + idx) = vV;
            *(f32x4*)(outW + idx) = vW;
        }
    }
}

extern "C" void kernel_launch(void* const* d_in, const int* in_sizes, int n_in,
                              void* d_out, int out_size, void* d_ws, size_t ws_size,
                              hipStream_t stream) {
    const float* x   = (const float*)d_in[0];
    const float* W   = (const float*)d_in[1];
    const float* gNa = (const float*)d_in[2];
    const float* gK  = (const float*)d_in[3];
    const float* gL  = (const float*)d_in[4];
    float* out = (float*)d_out;
    (void)d_ws; (void)ws_size;  // no workspace: avoids its poison-fill cost

    hipLaunchKernelGGL(snn_fused_kernel, dim3(1024), dim3(256), 0, stream,
                       x, W, gNa, gK, gL, out);
}

// Round 3
// 158.454 us; speedup vs baseline: 1.1282x; 1.0266x over previous
//
#include <hip/hip_runtime.h>
#include <hip/hip_bf16.h>
#include <math.h>

typedef __bf16 bf16x8 __attribute__((ext_vector_type(8)));
typedef float  f32x4  __attribute__((ext_vector_type(4)));

#define M_DIM 16384
#define N_DIM 512
#define K_DIM 512
#define TBL_N 1024

__device__ inline bf16x8 cvt8(float4 a, float4 b) {
    bf16x8 r;
    r[0] = (__bf16)a.x; r[1] = (__bf16)a.y; r[2] = (__bf16)a.z; r[3] = (__bf16)a.w;
    r[4] = (__bf16)b.x; r[5] = (__bf16)b.y; r[6] = (__bf16)b.z; r[7] = (__bf16)b.w;
    return r;
}

// ---------------- fused fp32->bf16 GEMM + HH, double-buffered LDS ----------------
// R12: R11 was latency-bound (MfmaUtil 5%, VALUBusy 21%, HBM 26%, all pipes
// idle) -- the 2-barrier/K-tile single-buffer structure serializes
// stage->barrier->MFMA->barrier with too few resident blocks to overlap.
// Changes:
//   1. LDS double-buffer, ONE barrier per K-tile. MFMA reads of buf[cur] come
//      FIRST in program order (lgkmcnt waits only on the reads), staging
//      writes to buf[cur^1] after, then the single barrier. (R9's dbuf
//      regression was a global_load_lds/vmcnt-alias artifact; reg-staging
//      orders via lgkmcnt precisely.)
//   2. W register prefetch restored (R10 failed only due to the 64-VGPR cap;
//      (256,3) caps at 168). Tile t+2 loads issue during iter t staging =>
//      one full MFMA phase + barrier of latency slack.
// LDS: 2*(8K+16K)+4.1K = 53.3 KB -> 3 blocks/CU.
__global__ __launch_bounds__(256, 3)
void snn_fused_kernel(const float* __restrict__ x, const float* __restrict__ W,
                      const float* __restrict__ gNa_p, const float* __restrict__ gK_p,
                      const float* __restrict__ gL_p, float* __restrict__ out)
{
    __shared__ __bf16 sW[2][64 * 64];     // W-tile: 64 gn rows x 64 k
    __shared__ __bf16 sX[2][128 * 64];    // x-tile: 128 gm rows x 64 k
    __shared__ float  tbl[TBL_N + 1];

    const int tid = threadIdx.x;

    // XCD swizzle: each XCD owns 16 bm tiles; consecutive slots sweep all 8 bn
    // for one bm so the x-rows stay L2-resident across their reuse.
    const int id   = blockIdx.x;            // 0..1023
    const int xcd  = id & 7;
    const int slot = id >> 3;               // 0..127
    const int bm   = xcd * 16 + (slot >> 3);    // 0..127
    const int bn   = slot & 7;                  // 0..7

    const int wv   = tid >> 6;
    const int ln   = tid & 63;
    const int lr   = ln & 15;
    const int quad = ln >> 4;

    // staging pattern: lane covers row rw of an 8-row group, 16B-chunk ch.
    // Source column is XOR-swizzled (chx); LDS dest linear chunk ch =>
    // LDS[r][c] holds global chunk c^(r&7); MFMA read applies the same XOR.
    const int rw  = ln >> 3;                // 0..7
    const int ch  = ln & 7;                 // 0..7
    const int chx = (ch ^ rw) * 8;          // swizzled k-offset within tile

    const float* wSrc = W + ((long)bn * 64 + 16 * wv + rw) * K_DIM + chx;
    const float* xSrc = x + ((long)bm * 128 + 32 * wv + rw) * K_DIM + chx;
    const int wOff = (16 * wv + rw) * 64 + ch * 8;
    const int xOff = (32 * wv + rw) * 64 + ch * 8;

    // ---- issue tile-0 loads (arrive during the table build) ----
    float4 px[4][2], pw[2][2];              // 48 VGPRs of prefetch state
    #pragma unroll
    for (int j = 0; j < 2; ++j) {
        pw[j][0] = *(const float4*)(wSrc + (long)(8 * j) * K_DIM);
        pw[j][1] = *(const float4*)(wSrc + (long)(8 * j) * K_DIM + 4);
    }
    #pragma unroll
    for (int j = 0; j < 4; ++j) {
        px[j][0] = *(const float4*)(xSrc + (long)(8 * j) * K_DIM);
        px[j][1] = *(const float4*)(xSrc + (long)(8 * j) * K_DIM + 4);
    }

    // ---- exact-HH I_in(V) table (overlaps tile-0 load latency) ----
    {
        const float gNa = *gNa_p, gK = *gK_p, gL = *gL_p;
        for (int i = tid; i <= TBL_N; i += 256) {
            const float V = -4.0f + (8.0f / TBL_N) * i;
            const float am = 0.1f * (V + 40.0f) / (1.0f - expf(-(V + 40.0f) * 0.1f));
            const float bm_ = 4.0f * expf(-(V + 65.0f) * (1.0f / 18.0f));
            const float ah = 0.07f * expf(-(V + 65.0f) * 0.05f);
            const float bh = 1.0f / (1.0f + expf(-(V + 35.0f) * 0.1f));
            const float an = 0.01f * (V + 55.0f) / (1.0f - expf(-(V + 55.0f) * 0.1f));
            const float bn_ = 0.125f * expf(-(V + 65.0f) * 0.0125f);
            const float m = 0.05f + 0.1f * (am * 0.95f - bm_ * 0.05f);
            const float h = 0.60f + 0.1f * (ah * 0.40f - bh * 0.60f);
            const float n = 0.32f + 0.1f * (an * 0.68f - bn_ * 0.32f);
            tbl[i] = gNa * m * m * m * h * (V - 50.0f)
                   + gK * (n * n) * (n * n) * (V + 77.0f)
                   + gL * (V + 54.4f) + V;
        }
    }

    // ---- prologue: stage tile 0 into buf0, issue tile-1 loads ----
    #pragma unroll
    for (int j = 0; j < 2; ++j) {
        float4 a = pw[j][0], b = pw[j][1];
        pw[j][0] = *(const float4*)(wSrc + (long)(8 * j) * K_DIM + 64);
        pw[j][1] = *(const float4*)(wSrc + (long)(8 * j) * K_DIM + 64 + 4);
        *(bf16x8*)(&sW[0][wOff + 8 * j * 64]) = cvt8(a, b);
    }
    #pragma unroll
    for (int j = 0; j < 4; ++j) {
        float4 a = px[j][0], b = px[j][1];
        px[j][0] = *(const float4*)(xSrc + (long)(8 * j) * K_DIM + 64);
        px[j][1] = *(const float4*)(xSrc + (long)(8 * j) * K_DIM + 64 + 4);
        *(bf16x8*)(&sX[0][xOff + 8 * j * 64]) = cvt8(a, b);
    }
    __syncthreads();   // tile 0 resident, tbl built

    f32x4 acc[4][2] = {};   // [gn frag f][gm frag g]

    for (int t = 0; t < 8; ++t) {
        const int cur = t & 1;
        // ---- MFMA phase on buf[cur] (reads first in program order) ----
        #pragma unroll
        for (int kk = 0; kk < 2; ++kk) {
            const int cidx = quad + 4 * kk;
            const int sl   = (cidx ^ (lr & 7)) * 8;
            bf16x8 aw[4], bx[2];
            #pragma unroll
            for (int f = 0; f < 4; ++f)
                aw[f] = *(const bf16x8*)(&sW[cur][(f * 16 + lr) * 64 + sl]);
            #pragma unroll
            for (int g = 0; g < 2; ++g)
                bx[g] = *(const bf16x8*)(&sX[cur][(32 * wv + g * 16 + lr) * 64 + sl]);
            #pragma unroll
            for (int f = 0; f < 4; ++f)
                #pragma unroll
                for (int g = 0; g < 2; ++g)
                    acc[f][g] = __builtin_amdgcn_mfma_f32_16x16x32_bf16(
                        aw[f], bx[g], acc[f][g], 0, 0, 0);
        }
        // ---- stage tile t+1 into buf[cur^1]; issue tile t+2 loads ----
        if (t < 7) {
            const int nk = (t + 2) * 64;
            #pragma unroll
            for (int j = 0; j < 2; ++j) {
                float4 a = pw[j][0], b = pw[j][1];
                if (t < 6) {
                    pw[j][0] = *(const float4*)(wSrc + (long)(8 * j) * K_DIM + nk);
                    pw[j][1] = *(const float4*)(wSrc + (long)(8 * j) * K_DIM + nk + 4);
                }
                *(bf16x8*)(&sW[cur ^ 1][wOff + 8 * j * 64]) = cvt8(a, b);
            }
            #pragma unroll
            for (int j = 0; j < 4; ++j) {
                float4 a = px[j][0], b = px[j][1];
                if (t < 6) {
                    px[j][0] = *(const float4*)(xSrc + (long)(8 * j) * K_DIM + nk);
                    px[j][1] = *(const float4*)(xSrc + (long)(8 * j) * K_DIM + nk + 4);
                }
                *(bf16x8*)(&sX[cur ^ 1][xOff + 8 * j * 64]) = cvt8(a, b);
            }
            __syncthreads();   // buf[cur^1] resident; buf[cur] free to overwrite
        }
    }

    // ---- float4 epilogue: 4 consecutive gn per thread per frag ----
    float* outS = out;
    float* outV = out + (long)M_DIM * N_DIM;
    float* outW = out + 2L * M_DIM * N_DIM;

    #pragma unroll
    for (int f = 0; f < 4; ++f) {
        const int gn4 = bn * 64 + f * 16 + quad * 4;
        #pragma unroll
        for (int g = 0; g < 2; ++g) {
            const long gm  = (long)bm * 128 + 32 * wv + g * 16 + lr;
            const long idx = gm * N_DIM + gn4;
            f32x4 vS, vV, vW;
            #pragma unroll
            for (int i = 0; i < 4; ++i) {
                const float V = acc[f][g][i];
                float u = (V + 4.0f) * (TBL_N / 8.0f);
                u = fminf(fmaxf(u, 0.0f), (float)TBL_N - 0.001f);
                const int   iu = (int)u;
                const float fr = u - (float)iu;
                const float I_in = tbl[iu] + fr * (tbl[iu + 1] - tbl[iu]);
                const float v_new = -65.0f + I_in * 0.005f;
                const float spike = (v_new >= -50.0f) ? 1.0f : 0.0f;
                vS[i] = spike;
                vW[i] = (0.5f * (v_new + 65.0f) + 0.1f * spike) * 0.001f;
                vV[i] = (spike > 0.5f) ? -65.0f : v_new;
            }
            *(f32x4*)(outS + idx) = vS;
            *(f32x4*)(outV + idx) = vV;
            *(f32x4*)(outW + idx) = vW;
        }
    }
}

extern "C" void kernel_launch(void* const* d_in, const int* in_sizes, int n_in,
                              void* d_out, int out_size, void* d_ws, size_t ws_size,
                              hipStream_t stream) {
    const float* x   = (const float*)d_in[0];
    const float* W   = (const float*)d_in[1];
    const float* gNa = (const float*)d_in[2];
    const float* gK  = (const float*)d_in[3];
    const float* gL  = (const float*)d_in[4];
    float* out = (float*)d_out;
    (void)d_ws; (void)ws_size;  // no workspace: avoids its poison-fill cost

    hipLaunchKernelGGL(snn_fused_kernel, dim3(1024), dim3(256), 0, stream,
                       x, W, gNa, gK, gL, out);
}